// Round 6
// baseline (158.189 us; speedup 1.0000x reference)
//
#include <hip/hip_runtime.h>
#include <stdint.h>

#define B_ 2
#define T_ 2048
#define C_ 1024
#define H_ 16
#define D_ 64
#define M_ (B_*T_)
#define BHTD_ (B_*H_*T_*D_)

typedef __bf16 bf16x8 __attribute__((ext_vector_type(8)));
typedef __bf16 bf16x4 __attribute__((ext_vector_type(4)));
typedef float f32x4 __attribute__((ext_vector_type(4)));

static __device__ __forceinline__ unsigned short f32_bf16(float f) {
    unsigned int u = __float_as_uint(f);
    u += 0x7FFFu + ((u >> 16) & 1u);   // round-to-nearest-even
    return (unsigned short)(u >> 16);
}

// ---------------- cast f32 -> bf16 (vectorized) ----------------
__global__ void cast_kernel(const float* __restrict__ in, unsigned short* __restrict__ out, int n) {
    int i = (blockIdx.x * 256 + threadIdx.x) * 4;
    if (i >= n) return;
    float4 f = *(const float4*)(in + i);
    ushort4 o;
    o.x = f32_bf16(f.x); o.y = f32_bf16(f.y); o.z = f32_bf16(f.z); o.w = f32_bf16(f.w);
    *(ushort4*)(out + i) = o;
}

// ---------------- transpose+cast: W [K][N] f32 -> Wt [N][K] bf16 ----------------
__global__ void transpose_cast_kernel(const float* __restrict__ W, unsigned short* __restrict__ Wt,
                                      int K, int N) {
    __shared__ float tile[32][33];
    int n0 = blockIdx.x * 32, k0 = blockIdx.y * 32;
    int tx = threadIdx.x, ty = threadIdx.y;
    #pragma unroll
    for (int j = 0; j < 32; j += 8)
        tile[ty + j][tx] = W[(size_t)(k0 + ty + j) * N + n0 + tx];
    __syncthreads();
    #pragma unroll
    for (int j = 0; j < 32; j += 8)
        Wt[(size_t)(n0 + ty + j) * K + k0 + tx] = f32_bf16(tile[tx][ty + j]);
}

// ---------------- GEMM: C[M][N] = A[M][K](bf16) * Bt[N][K]^T(bf16) + bias ----------------
// m97 structure: global_load_lds width-16 staging, linear LDS [128][32].
// XCD-aware bijective swizzle on the flattened grid (T1).
// EPI=0: scatter bf16 into qkv (q scaled by log2e/sqrt(D)); EPI=1: f32 out.
template<int EPI>
__global__ __launch_bounds__(256) void gemm_bt(
    const unsigned short* __restrict__ A,
    const unsigned short* __restrict__ Bt,
    const float* __restrict__ bias,
    unsigned short* __restrict__ out_bf16,
    float* __restrict__ out_f32,
    int M, int N, int K)
{
    __shared__ unsigned short As[128 * 32];
    __shared__ unsigned short Bs[128 * 32];
    int tid = threadIdx.x;
    int lane = tid & 63, wid = tid >> 6;
    int fr = lane & 15, fg = lane >> 4;

    // XCD swizzle (nwg % 8 == 0 for both grids)
    int lin = blockIdx.y * gridDim.x + blockIdx.x;
    int cpx = (gridDim.x * gridDim.y) >> 3;
    int swz = (lin & 7) * cpx + (lin >> 3);
    int row0 = (swz % gridDim.x) * 128, col0 = (swz / gridDim.x) * 128;

    int wm = (wid >> 1) * 64, wn = (wid & 1) * 64;

    f32x4 acc[4][4];
    #pragma unroll
    for (int i = 0; i < 4; ++i)
        #pragma unroll
        for (int j = 0; j < 4; ++j)
            acc[i][j] = (f32x4){0.f, 0.f, 0.f, 0.f};

    const int srw = lane >> 2;
    const int scl = (lane & 3) * 8;
    const int c0 = wid * 2, c1 = wid * 2 + 1;

    for (int k0 = 0; k0 < K; k0 += 32) {
        __syncthreads();
        __builtin_amdgcn_global_load_lds(
            (const __attribute__((address_space(1))) void*)(A + (size_t)(row0 + c0 * 16 + srw) * K + k0 + scl),
            (__attribute__((address_space(3))) void*)(As + c0 * 512), 16, 0, 0);
        __builtin_amdgcn_global_load_lds(
            (const __attribute__((address_space(1))) void*)(A + (size_t)(row0 + c1 * 16 + srw) * K + k0 + scl),
            (__attribute__((address_space(3))) void*)(As + c1 * 512), 16, 0, 0);
        __builtin_amdgcn_global_load_lds(
            (const __attribute__((address_space(1))) void*)(Bt + (size_t)(col0 + c0 * 16 + srw) * K + k0 + scl),
            (__attribute__((address_space(3))) void*)(Bs + c0 * 512), 16, 0, 0);
        __builtin_amdgcn_global_load_lds(
            (const __attribute__((address_space(1))) void*)(Bt + (size_t)(col0 + c1 * 16 + srw) * K + k0 + scl),
            (__attribute__((address_space(3))) void*)(Bs + c1 * 512), 16, 0, 0);
        __syncthreads();

        bf16x8 af[4], bfr[4];
        #pragma unroll
        for (int i = 0; i < 4; ++i) {
            af[i]  = *(const bf16x8*)(As + (wm + i * 16 + fr) * 32 + fg * 8);
            bfr[i] = *(const bf16x8*)(Bs + (wn + i * 16 + fr) * 32 + fg * 8);
        }
        #pragma unroll
        for (int mi = 0; mi < 4; ++mi)
            #pragma unroll
            for (int ni = 0; ni < 4; ++ni)
                acc[mi][ni] = __builtin_amdgcn_mfma_f32_16x16x32_bf16(af[mi], bfr[ni], acc[mi][ni], 0, 0, 0);
    }

    #pragma unroll
    for (int mi = 0; mi < 4; ++mi) {
        int rowb = row0 + wm + mi * 16 + fg * 4;
        #pragma unroll
        for (int ni = 0; ni < 4; ++ni) {
            int col = col0 + wn + ni * 16 + fr;
            float bv = bias[col];
            #pragma unroll
            for (int r = 0; r < 4; ++r) {
                float v = acc[mi][ni][r] + bv;
                int rr = rowb + r;
                if (EPI == 0) {
                    int part = col >> 10, c = col & 1023;
                    int h = c >> 6, d = c & 63;
                    int b = rr >> 11, t = rr & 2047;
                    if (part == 0) v *= 0.18033688011112042f;   // fold log2(e)/sqrt(D) into Q
                    size_t idx;
                    if (part == 2)
                        idx = (size_t)2 * BHTD_ + ((size_t)(b * H_ + h) * D_ + d) * T_ + t;
                    else
                        idx = (size_t)part * BHTD_ + ((size_t)(b * H_ + h) * T_ + t) * D_ + d;
                    out_bf16[idx] = f32_bf16(v);
                } else {
                    out_f32[(size_t)rr * N + col] = v;
                }
            }
        }
    }
}

// ---------------- causal flash attention v6: swapped-operand QK/PV ----------------
// S^T = mfma(K, Q): lane holds P for ONE q row, kv-consecutive groups of 4.
// -> packed b64 P writes, per-lane l, O^T = mfma(V^T, P^T), packed y stores.
// K/V^T dbuf in swizzled LDS; prefetch t+1 before compute t; XCD/balance swizzle.
__global__ __launch_bounds__(256) void attn_kernel(
    const unsigned short* __restrict__ qg,
    const unsigned short* __restrict__ kg,
    const unsigned short* __restrict__ vtg,  // [bh][D][T]
    unsigned short* __restrict__ y)
{
    const int id = blockIdx.x;
    const int xcd = id & 7, loc = id >> 3;
    const int bh = xcd * 4 + (loc & 3);
    const int j = loc >> 2;
    const int qb = (j < 8) ? (15 - 2 * j) : (2 * (j - 8));
    const int b = bh >> 4, h = bh & 15;
    const int tid = threadIdx.x, wid = tid >> 6, lane = tid & 63;
    const int fr = lane & 15, fg = lane >> 4;

    const unsigned short* qp = qg + (size_t)bh * (T_ * D_);
    const unsigned short* kp = kg + (size_t)bh * (T_ * D_);
    const unsigned short* vp = vtg + (size_t)bh * (D_ * T_);

    __shared__ __align__(16) char Ks[2][64 * 128];          // [kv][d] bf16, swizzled
    __shared__ __align__(16) char Vs[2][64 * 128];          // [d][kv] bf16, swizzled
    __shared__ __align__(16) char Ps[4][32 * 128];          // per-wave P [32q][64kv], swizzled
    char* Pw = Ps[wid];

    const int r0 = qb * 128 + wid * 32;

    const int srow = tid >> 3;
    const int scb  = (tid & 7) * 16;
    const int sws  = scb ^ ((srow & 7) << 4);

    // Q fragments (pre-scaled by log2e/sqrt(D)); used as the B-operand of mfma(K,Q)
    bf16x8 qf[2][2];
    #pragma unroll
    for (int m = 0; m < 2; ++m)
        #pragma unroll
        for (int kd = 0; kd < 2; ++kd)
            qf[m][kd] = *(const bf16x8*)(qp + (size_t)(r0 + m * 16 + fr) * D_ + kd * 32 + fg * 8);

    // O^T accumulators: oT[m][nd][r] = O[q=r0+m*16+fr][d=nd*16+fg*4+r]
    f32x4 oT[2][4];
    float lrun[2];
    #pragma unroll
    for (int m = 0; m < 2; ++m) {
        lrun[m] = 0.f;
        #pragma unroll
        for (int n = 0; n < 4; ++n) oT[m][n] = (f32x4){0.f, 0.f, 0.f, 0.f};
    }

    const int ntk = 2 * (qb + 1);

    // prologue: stage tile 0 into buffer 0
    {
        uint4 k0 = *(const uint4*)(kp + (size_t)srow        * D_ + (scb >> 1));
        uint4 k1 = *(const uint4*)(kp + (size_t)(srow + 32) * D_ + (scb >> 1));
        uint4 v0 = *(const uint4*)(vp + (size_t)srow        * T_ + (scb >> 1));
        uint4 v1 = *(const uint4*)(vp + (size_t)(srow + 32) * T_ + (scb >> 1));
        *(uint4*)(Ks[0] + srow * 128 + sws)        = k0;
        *(uint4*)(Ks[0] + (srow + 32) * 128 + sws) = k1;
        *(uint4*)(Vs[0] + srow * 128 + sws)        = v0;
        *(uint4*)(Vs[0] + (srow + 32) * 128 + sws) = v1;
    }
    __syncthreads();

    int cur = 0;
    for (int t = 0; t < ntk; ++t) {
        const int kv0 = t * 64;
        const int kv1 = (t + 1 < ntk) ? kv0 + 64 : kv0;

        // prefetch tile t+1 (global->reg; lands under this tile's compute)
        uint4 pk0 = *(const uint4*)(kp + (size_t)(kv1 + srow)      * D_ + (scb >> 1));
        uint4 pk1 = *(const uint4*)(kp + (size_t)(kv1 + srow + 32) * D_ + (scb >> 1));
        uint4 pv0 = *(const uint4*)(vp + (size_t)srow        * T_ + kv1 + (scb >> 1));
        uint4 pv1 = *(const uint4*)(vp + (size_t)(srow + 32) * T_ + kv1 + (scb >> 1));

        const bool active = (kv0 <= r0 + 31);
        if (active) {
            const char* Kb = Ks[cur];
            const char* Vb = Vs[cur];
            const unsigned lsw = (unsigned)((fr & 7) << 4);

            // S^T = mfma(K, Q): s[m][n][r] = S[q=r0+m*16+fr][kv=kv0+n*16+fg*4+r]
            f32x4 s[2][4];
            #pragma unroll
            for (int m = 0; m < 2; ++m)
                #pragma unroll
                for (int n = 0; n < 4; ++n) s[m][n] = (f32x4){0.f, 0.f, 0.f, 0.f};
            #pragma unroll
            for (int kd = 0; kd < 2; ++kd)
                #pragma unroll
                for (int n = 0; n < 4; ++n) {
                    bf16x8 kf = *(const bf16x8*)(Kb + (n * 16 + fr) * 128 +
                                                 (((unsigned)(kd * 64 + fg * 16)) ^ lsw));
                    #pragma unroll
                    for (int m = 0; m < 2; ++m)
                        s[m][n] = __builtin_amdgcn_mfma_f32_16x16x32_bf16(kf, qf[m][kd], s[m][n], 0, 0, 0);
                }

            // no-max softmax; P row is lane-local, kv groups of 4 -> packed b64 writes
            const bool masked = (kv0 + 63 > r0);
            #pragma unroll
            for (int m = 0; m < 2; ++m) {
                const int qrow = r0 + m * 16 + fr;
                const unsigned prow = (unsigned)(m * 16 + fr) * 128;
                #pragma unroll
                for (int n = 0; n < 4; ++n) {
                    float x0 = s[m][n][0], x1 = s[m][n][1];
                    float x2 = s[m][n][2], x3 = s[m][n][3];
                    if (masked) {
                        const int kvb = kv0 + n * 16 + fg * 4;
                        if (kvb     > qrow) x0 = -1e30f;
                        if (kvb + 1 > qrow) x1 = -1e30f;
                        if (kvb + 2 > qrow) x2 = -1e30f;
                        if (kvb + 3 > qrow) x3 = -1e30f;
                    }
                    const float p0 = exp2f(x0);
                    const float p1 = exp2f(x1);
                    const float p2 = exp2f(x2);
                    const float p3 = exp2f(x3);
                    lrun[m] += (p0 + p1) + (p2 + p3);
                    bf16x4 pk4 = {(__bf16)p0, (__bf16)p1, (__bf16)p2, (__bf16)p3};
                    *(uint2*)(Pw + ((prow + (unsigned)(n * 32 + fg * 8)) ^ lsw)) =
                        __builtin_bit_cast(uint2, pk4);
                }
            }
            asm volatile("s_waitcnt lgkmcnt(0)" ::: "memory");
            __builtin_amdgcn_sched_barrier(0);

            // O^T += V^T P^T : A = V^T frags (LDS), B = P^T frags (contig b128)
            bf16x8 vf[4][2];
            #pragma unroll
            for (int nd = 0; nd < 4; ++nd)
                #pragma unroll
                for (int kk = 0; kk < 2; ++kk)
                    vf[nd][kk] = *(const bf16x8*)(Vb + (nd * 16 + fr) * 128 +
                                                  (((unsigned)(kk * 64 + fg * 16)) ^ lsw));
            #pragma unroll
            for (int m = 0; m < 2; ++m) {
                const unsigned prow = (unsigned)(m * 16 + fr) * 128;
                #pragma unroll
                for (int kk = 0; kk < 2; ++kk) {
                    bf16x8 pb = *(const bf16x8*)(Pw + ((prow + (unsigned)(kk * 64 + fg * 16)) ^ lsw));
                    #pragma unroll
                    for (int nd = 0; nd < 4; ++nd)
                        oT[m][nd] = __builtin_amdgcn_mfma_f32_16x16x32_bf16(vf[nd][kk], pb, oT[m][nd], 0, 0, 0);
                }
            }
        }

        // write prefetched tile into the other buffer, then barrier
        {
            char* Kn = Ks[cur ^ 1];
            char* Vn = Vs[cur ^ 1];
            *(uint4*)(Kn + srow * 128 + sws)        = pk0;
            *(uint4*)(Kn + (srow + 32) * 128 + sws) = pk1;
            *(uint4*)(Vn + srow * 128 + sws)        = pv0;
            *(uint4*)(Vn + (srow + 32) * 128 + sws) = pv1;
        }
        __syncthreads();
        cur ^= 1;
    }

    // epilogue: reduce l across fg groups (same q row), normalize, packed stores
    #pragma unroll
    for (int m = 0; m < 2; ++m) {
        float rs = lrun[m];
        rs += __shfl_xor(rs, 16);
        rs += __shfl_xor(rs, 32);
        const float inv = 1.f / rs;
        const int trow = r0 + m * 16 + fr;
        #pragma unroll
        for (int nd = 0; nd < 4; ++nd) {
            bf16x4 ov = {(__bf16)(oT[m][nd][0] * inv), (__bf16)(oT[m][nd][1] * inv),
                         (__bf16)(oT[m][nd][2] * inv), (__bf16)(oT[m][nd][3] * inv)};
            *(uint2*)(y + ((size_t)b * T_ + trow) * C_ + h * 64 + nd * 16 + fg * 4) =
                __builtin_bit_cast(uint2, ov);
        }
    }
}

// ---------------- launch ----------------
extern "C" void kernel_launch(void* const* d_in, const int* in_sizes, int n_in,
                              void* d_out, int out_size, void* d_ws, size_t ws_size,
                              hipStream_t stream) {
    const float* x     = (const float*)d_in[0];
    const float* Wqkv  = (const float*)d_in[1];
    const float* bqkv  = (const float*)d_in[2];
    const float* Wproj = (const float*)d_in[3];
    const float* bproj = (const float*)d_in[4];
    float* out = (float*)d_out;

    char* ws = (char*)d_ws;
    unsigned short* x_bf    = (unsigned short*)(ws);                 //  8 MB
    unsigned short* wqkv_t  = (unsigned short*)(ws + 8388608);       //  6 MB
    unsigned short* wproj_t = (unsigned short*)(ws + 14680064);      //  2 MB
    unsigned short* qkv     = (unsigned short*)(ws + 16777216);      // 24 MB
    unsigned short* ybuf    = (unsigned short*)(ws + 41943040);      //  8 MB

    cast_kernel<<<(M_ * C_) / 4 / 256, 256, 0, stream>>>(x, x_bf, M_ * C_);
    transpose_cast_kernel<<<dim3(3072 / 32, 1024 / 32), dim3(32, 8), 0, stream>>>(Wqkv, wqkv_t, 1024, 3072);
    transpose_cast_kernel<<<dim3(1024 / 32, 1024 / 32), dim3(32, 8), 0, stream>>>(Wproj, wproj_t, 1024, 1024);

    gemm_bt<0><<<dim3(M_ / 128, 3072 / 128), 256, 0, stream>>>(
        x_bf, wqkv_t, bqkv, qkv, nullptr, M_, 3072, 1024);

    attn_kernel<<<dim3(512), 256, 0, stream>>>(
        qkv, qkv + (size_t)BHTD_, qkv + 2 * (size_t)BHTD_, ybuf);

    gemm_bt<1><<<dim3(M_ / 128, 1024 / 128), 256, 0, stream>>>(
        ybuf, wproj_t, bproj, nullptr, out, M_, 1024, 1024);
}

// Round 7
// 133.655 us; speedup vs baseline: 1.1836x; 1.1836x over previous
//
#include <hip/hip_runtime.h>
#include <stdint.h>

#define B_ 2
#define T_ 2048
#define C_ 1024
#define H_ 16
#define D_ 64
#define M_ (B_*T_)
#define BHTD_ (B_*H_*T_*D_)

typedef __bf16 bf16x8 __attribute__((ext_vector_type(8)));
typedef __bf16 bf16x4 __attribute__((ext_vector_type(4)));
typedef float f32x4 __attribute__((ext_vector_type(4)));

static __device__ __forceinline__ unsigned short f32_bf16(float f) {
    unsigned int u = __float_as_uint(f);
    u += 0x7FFFu + ((u >> 16) & 1u);   // round-to-nearest-even
    return (unsigned short)(u >> 16);
}

// ---------------- cast f32 -> bf16 (vectorized) ----------------
__global__ void cast_kernel(const float* __restrict__ in, unsigned short* __restrict__ out, int n) {
    int i = (blockIdx.x * 256 + threadIdx.x) * 4;
    if (i >= n) return;
    float4 f = *(const float4*)(in + i);
    ushort4 o;
    o.x = f32_bf16(f.x); o.y = f32_bf16(f.y); o.z = f32_bf16(f.z); o.w = f32_bf16(f.w);
    *(ushort4*)(out + i) = o;
}

// ---------------- transpose+cast: W [K][N] f32 -> Wt [N][K] bf16 ----------------
__global__ void transpose_cast_kernel(const float* __restrict__ W, unsigned short* __restrict__ Wt,
                                      int K, int N) {
    __shared__ float tile[32][33];
    int n0 = blockIdx.x * 32, k0 = blockIdx.y * 32;
    int tx = threadIdx.x, ty = threadIdx.y;
    #pragma unroll
    for (int j = 0; j < 32; j += 8)
        tile[ty + j][tx] = W[(size_t)(k0 + ty + j) * N + n0 + tx];
    __syncthreads();
    #pragma unroll
    for (int j = 0; j < 32; j += 8)
        Wt[(size_t)(n0 + ty + j) * K + k0 + tx] = f32_bf16(tile[tx][ty + j]);
}

// ---------------- GEMM: C[M][N] = A[M][K](bf16) * Bt[N][K]^T(bf16) + bias ----------------
// m97 structure: global_load_lds width-16 staging into linear LDS [128][32].
// (round-5 version: NO grid swizzle — natural dispatch order has better L2 locality)
template<int EPI>
__global__ __launch_bounds__(256) void gemm_bt(
    const unsigned short* __restrict__ A,
    const unsigned short* __restrict__ Bt,
    const float* __restrict__ bias,
    unsigned short* __restrict__ out_bf16,
    float* __restrict__ out_f32,
    int M, int N, int K)
{
    __shared__ unsigned short As[128 * 32];
    __shared__ unsigned short Bs[128 * 32];
    int tid = threadIdx.x;
    int lane = tid & 63, wid = tid >> 6;
    int fr = lane & 15, fg = lane >> 4;
    int row0 = blockIdx.x * 128, col0 = blockIdx.y * 128;
    int wm = (wid >> 1) * 64, wn = (wid & 1) * 64;

    f32x4 acc[4][4];
    #pragma unroll
    for (int i = 0; i < 4; ++i)
        #pragma unroll
        for (int j = 0; j < 4; ++j)
            acc[i][j] = (f32x4){0.f, 0.f, 0.f, 0.f};

    const int srw = lane >> 2;
    const int scl = (lane & 3) * 8;
    const int c0 = wid * 2, c1 = wid * 2 + 1;

    for (int k0 = 0; k0 < K; k0 += 32) {
        __syncthreads();
        __builtin_amdgcn_global_load_lds(
            (const __attribute__((address_space(1))) void*)(A + (size_t)(row0 + c0 * 16 + srw) * K + k0 + scl),
            (__attribute__((address_space(3))) void*)(As + c0 * 512), 16, 0, 0);
        __builtin_amdgcn_global_load_lds(
            (const __attribute__((address_space(1))) void*)(A + (size_t)(row0 + c1 * 16 + srw) * K + k0 + scl),
            (__attribute__((address_space(3))) void*)(As + c1 * 512), 16, 0, 0);
        __builtin_amdgcn_global_load_lds(
            (const __attribute__((address_space(1))) void*)(Bt + (size_t)(col0 + c0 * 16 + srw) * K + k0 + scl),
            (__attribute__((address_space(3))) void*)(Bs + c0 * 512), 16, 0, 0);
        __builtin_amdgcn_global_load_lds(
            (const __attribute__((address_space(1))) void*)(Bt + (size_t)(col0 + c1 * 16 + srw) * K + k0 + scl),
            (__attribute__((address_space(3))) void*)(Bs + c1 * 512), 16, 0, 0);
        __syncthreads();

        bf16x8 af[4], bfr[4];
        #pragma unroll
        for (int i = 0; i < 4; ++i) {
            af[i]  = *(const bf16x8*)(As + (wm + i * 16 + fr) * 32 + fg * 8);
            bfr[i] = *(const bf16x8*)(Bs + (wn + i * 16 + fr) * 32 + fg * 8);
        }
        #pragma unroll
        for (int mi = 0; mi < 4; ++mi)
            #pragma unroll
            for (int ni = 0; ni < 4; ++ni)
                acc[mi][ni] = __builtin_amdgcn_mfma_f32_16x16x32_bf16(af[mi], bfr[ni], acc[mi][ni], 0, 0, 0);
    }

    #pragma unroll
    for (int mi = 0; mi < 4; ++mi) {
        int rowb = row0 + wm + mi * 16 + fg * 4;
        #pragma unroll
        for (int ni = 0; ni < 4; ++ni) {
            int col = col0 + wn + ni * 16 + fr;
            float bv = bias[col];
            #pragma unroll
            for (int r = 0; r < 4; ++r) {
                float v = acc[mi][ni][r] + bv;
                int rr = rowb + r;
                if (EPI == 0) {
                    int part = col >> 10, c = col & 1023;
                    int h = c >> 6, d = c & 63;
                    int b = rr >> 11, t = rr & 2047;
                    if (part == 0) v *= 0.18033688011112042f;   // fold log2(e)/sqrt(D) into Q
                    size_t idx;
                    if (part == 2)
                        idx = (size_t)2 * BHTD_ + ((size_t)(b * H_ + h) * D_ + d) * T_ + t;
                    else
                        idx = (size_t)part * BHTD_ + ((size_t)(b * H_ + h) * T_ + t) * D_ + d;
                    out_bf16[idx] = f32_bf16(v);
                } else {
                    out_f32[(size_t)rr * N + col] = v;
                }
            }
        }
    }
}

// ---------------- causal flash attention v7: dual-stream balanced blocks ----------------
// Block handles chunks chlo=i and chhi=31-i (64 q rows each); every block = 33
// stream-tile units -> all blocks equal duration, stable 2 blocks/CU (2 waves/SIMD).
// Each wave: 16 rows of each chunk as two independent streams sharing KV tiles.
// Swapped-operand QK/PV (S^T = mfma(K,Q), O^T = mfma(V^T,P^T)); no-max softmax;
// K/V^T dbuf in swizzled LDS; reg prefetch of t+1 before compute of t.
__global__ __launch_bounds__(256) void attn_kernel(
    const unsigned short* __restrict__ qg,
    const unsigned short* __restrict__ kg,
    const unsigned short* __restrict__ vtg,  // [bh][D][T]
    unsigned short* __restrict__ y)
{
    const int id = blockIdx.x;
    const int xcd = id & 7, loc = id >> 3;
    const int bh = xcd * 4 + (loc & 3);      // 4 heads per XCD -> K/V L2-resident
    const int iq = loc >> 2;                 // [0,16)
    const int chlo = iq, chhi = 31 - iq;     // 64-row q chunks
    const int b = bh >> 4, h = bh & 15;
    const int tid = threadIdx.x, wid = tid >> 6, lane = tid & 63;
    const int fr = lane & 15, fg = lane >> 4;

    const unsigned short* qp = qg + (size_t)bh * (T_ * D_);
    const unsigned short* kp = kg + (size_t)bh * (T_ * D_);
    const unsigned short* vp = vtg + (size_t)bh * (D_ * T_);

    __shared__ __align__(16) char Ks[2][64 * 128];   // [kv][d] bf16, swizzled
    __shared__ __align__(16) char Vs[2][64 * 128];   // [d][kv] bf16, swizzled
    __shared__ __align__(16) char Ps[4][32 * 128];   // per-wave P: [stream*16+row][kv]
    char* Pw = Ps[wid];

    const int rhi = chhi * 64 + wid * 16;
    const int rlo = chlo * 64 + wid * 16;

    const int srow = tid >> 3;
    const int scb  = (tid & 7) * 16;
    const int sws  = scb ^ ((srow & 7) << 4);

    // Q fragments (pre-scaled by log2e/sqrt(D)); B-operand of mfma(K,Q)
    bf16x8 qhi[2], qlo[2];
    #pragma unroll
    for (int kd = 0; kd < 2; ++kd) {
        qhi[kd] = *(const bf16x8*)(qp + (size_t)(rhi + fr) * D_ + kd * 32 + fg * 8);
        qlo[kd] = *(const bf16x8*)(qp + (size_t)(rlo + fr) * D_ + kd * 32 + fg * 8);
    }

    // O^T accumulators: oX[nd][r] = O[q=rX+fr][d=nd*16+fg*4+r]
    f32x4 oHi[4], oLo[4];
    float lHi = 0.f, lLo = 0.f;
    #pragma unroll
    for (int n = 0; n < 4; ++n) {
        oHi[n] = (f32x4){0.f, 0.f, 0.f, 0.f};
        oLo[n] = (f32x4){0.f, 0.f, 0.f, 0.f};
    }

    const int ntk  = chhi + 1;   // 32 - iq KV tiles (hi stream span)
    const int ntlo = chlo + 1;   // iq + 1 KV tiles (lo stream span); always < ntk

    // prologue: stage tile 0 into buffer 0
    {
        uint4 k0 = *(const uint4*)(kp + (size_t)srow        * D_ + (scb >> 1));
        uint4 k1 = *(const uint4*)(kp + (size_t)(srow + 32) * D_ + (scb >> 1));
        uint4 v0 = *(const uint4*)(vp + (size_t)srow        * T_ + (scb >> 1));
        uint4 v1 = *(const uint4*)(vp + (size_t)(srow + 32) * T_ + (scb >> 1));
        *(uint4*)(Ks[0] + srow * 128 + sws)        = k0;
        *(uint4*)(Ks[0] + (srow + 32) * 128 + sws) = k1;
        *(uint4*)(Vs[0] + srow * 128 + sws)        = v0;
        *(uint4*)(Vs[0] + (srow + 32) * 128 + sws) = v1;
    }
    __syncthreads();

    int cur = 0;
    for (int t = 0; t < ntk; ++t) {
        const int kv0 = t * 64;
        const int kv1 = (t + 1 < ntk) ? kv0 + 64 : kv0;

        // prefetch tile t+1 global->reg (lands under this tile's compute)
        uint4 pk0 = *(const uint4*)(kp + (size_t)(kv1 + srow)      * D_ + (scb >> 1));
        uint4 pk1 = *(const uint4*)(kp + (size_t)(kv1 + srow + 32) * D_ + (scb >> 1));
        uint4 pv0 = *(const uint4*)(vp + (size_t)srow        * T_ + kv1 + (scb >> 1));
        uint4 pv1 = *(const uint4*)(vp + (size_t)(srow + 32) * T_ + kv1 + (scb >> 1));

        const char* Kb = Ks[cur];
        const char* Vb = Vs[cur];
        const unsigned lsw = (unsigned)((fr & 7) << 4);
        const bool lo_act = (t < ntlo);      // block-uniform

        // ---- S^T = mfma(K, Q), both streams (independent chains) ----
        f32x4 sh[4], sl[4];
        #pragma unroll
        for (int n = 0; n < 4; ++n) {
            sh[n] = (f32x4){0.f, 0.f, 0.f, 0.f};
            sl[n] = (f32x4){0.f, 0.f, 0.f, 0.f};
        }
        #pragma unroll
        for (int kd = 0; kd < 2; ++kd)
            #pragma unroll
            for (int n = 0; n < 4; ++n) {
                bf16x8 kf = *(const bf16x8*)(Kb + (n * 16 + fr) * 128 +
                                             (((unsigned)(kd * 64 + fg * 16)) ^ lsw));
                sh[n] = __builtin_amdgcn_mfma_f32_16x16x32_bf16(kf, qhi[kd], sh[n], 0, 0, 0);
                if (lo_act)
                    sl[n] = __builtin_amdgcn_mfma_f32_16x16x32_bf16(kf, qlo[kd], sl[n], 0, 0, 0);
            }

        // ---- softmax + P write, hi stream (masked only on diagonal tile) ----
        {
            const bool masked = (t == chhi);
            const int qrow = rhi + fr;
            const unsigned prow = (unsigned)fr * 128;          // stream 0 rows [0,16)
            #pragma unroll
            for (int n = 0; n < 4; ++n) {
                float x0 = sh[n][0], x1 = sh[n][1], x2 = sh[n][2], x3 = sh[n][3];
                if (masked) {
                    const int kvb = kv0 + n * 16 + fg * 4;
                    if (kvb     > qrow) x0 = -1e30f;
                    if (kvb + 1 > qrow) x1 = -1e30f;
                    if (kvb + 2 > qrow) x2 = -1e30f;
                    if (kvb + 3 > qrow) x3 = -1e30f;
                }
                const float p0 = exp2f(x0), p1 = exp2f(x1);
                const float p2 = exp2f(x2), p3 = exp2f(x3);
                lHi += (p0 + p1) + (p2 + p3);
                bf16x4 pk4 = {(__bf16)p0, (__bf16)p1, (__bf16)p2, (__bf16)p3};
                *(uint2*)(Pw + ((prow + (unsigned)(n * 32 + fg * 8)) ^ lsw)) =
                    __builtin_bit_cast(uint2, pk4);
            }
        }
        // ---- softmax + P write, lo stream ----
        if (lo_act) {
            const bool masked = (t == chlo);
            const int qrow = rlo + fr;
            const unsigned prow = (unsigned)(16 + fr) * 128;   // stream 1 rows [16,32)
            #pragma unroll
            for (int n = 0; n < 4; ++n) {
                float x0 = sl[n][0], x1 = sl[n][1], x2 = sl[n][2], x3 = sl[n][3];
                if (masked) {
                    const int kvb = kv0 + n * 16 + fg * 4;
                    if (kvb     > qrow) x0 = -1e30f;
                    if (kvb + 1 > qrow) x1 = -1e30f;
                    if (kvb + 2 > qrow) x2 = -1e30f;
                    if (kvb + 3 > qrow) x3 = -1e30f;
                }
                const float p0 = exp2f(x0), p1 = exp2f(x1);
                const float p2 = exp2f(x2), p3 = exp2f(x3);
                lLo += (p0 + p1) + (p2 + p3);
                bf16x4 pk4 = {(__bf16)p0, (__bf16)p1, (__bf16)p2, (__bf16)p3};
                *(uint2*)(Pw + ((prow + (unsigned)(n * 32 + fg * 8)) ^ lsw)) =
                    __builtin_bit_cast(uint2, pk4);
            }
        }
        asm volatile("s_waitcnt lgkmcnt(0)" ::: "memory");
        __builtin_amdgcn_sched_barrier(0);

        // ---- O^T += V^T P^T, shared V^T frags ----
        bf16x8 vf[4][2];
        #pragma unroll
        for (int nd = 0; nd < 4; ++nd)
            #pragma unroll
            for (int kk = 0; kk < 2; ++kk)
                vf[nd][kk] = *(const bf16x8*)(Vb + (nd * 16 + fr) * 128 +
                                              (((unsigned)(kk * 64 + fg * 16)) ^ lsw));
        {
            const unsigned prow = (unsigned)fr * 128;
            #pragma unroll
            for (int kk = 0; kk < 2; ++kk) {
                bf16x8 pb = *(const bf16x8*)(Pw + ((prow + (unsigned)(kk * 64 + fg * 16)) ^ lsw));
                #pragma unroll
                for (int nd = 0; nd < 4; ++nd)
                    oHi[nd] = __builtin_amdgcn_mfma_f32_16x16x32_bf16(vf[nd][kk], pb, oHi[nd], 0, 0, 0);
            }
        }
        if (lo_act) {
            const unsigned prow = (unsigned)(16 + fr) * 128;
            #pragma unroll
            for (int kk = 0; kk < 2; ++kk) {
                bf16x8 pb = *(const bf16x8*)(Pw + ((prow + (unsigned)(kk * 64 + fg * 16)) ^ lsw));
                #pragma unroll
                for (int nd = 0; nd < 4; ++nd)
                    oLo[nd] = __builtin_amdgcn_mfma_f32_16x16x32_bf16(vf[nd][kk], pb, oLo[nd], 0, 0, 0);
            }
        }

        // write prefetched tile into the other buffer, then barrier
        {
            char* Kn = Ks[cur ^ 1];
            char* Vn = Vs[cur ^ 1];
            *(uint4*)(Kn + srow * 128 + sws)        = pk0;
            *(uint4*)(Kn + (srow + 32) * 128 + sws) = pk1;
            *(uint4*)(Vn + srow * 128 + sws)        = pv0;
            *(uint4*)(Vn + (srow + 32) * 128 + sws) = pv1;
        }
        __syncthreads();
        cur ^= 1;
    }

    // ---- epilogue: reduce l over fg groups, normalize, packed stores ----
    #pragma unroll
    for (int s = 0; s < 2; ++s) {
        float rs = s ? lLo : lHi;
        rs += __shfl_xor(rs, 16);
        rs += __shfl_xor(rs, 32);
        const float inv = 1.f / rs;
        const int trow = (s ? rlo : rhi) + fr;
        f32x4* oT = s ? oLo : oHi;
        #pragma unroll
        for (int nd = 0; nd < 4; ++nd) {
            bf16x4 ov = {(__bf16)(oT[nd][0] * inv), (__bf16)(oT[nd][1] * inv),
                         (__bf16)(oT[nd][2] * inv), (__bf16)(oT[nd][3] * inv)};
            *(uint2*)(y + ((size_t)b * T_ + trow) * C_ + h * 64 + nd * 16 + fg * 4) =
                __builtin_bit_cast(uint2, ov);
        }
    }
}

// ---------------- launch ----------------
extern "C" void kernel_launch(void* const* d_in, const int* in_sizes, int n_in,
                              void* d_out, int out_size, void* d_ws, size_t ws_size,
                              hipStream_t stream) {
    const float* x     = (const float*)d_in[0];
    const float* Wqkv  = (const float*)d_in[1];
    const float* bqkv  = (const float*)d_in[2];
    const float* Wproj = (const float*)d_in[3];
    const float* bproj = (const float*)d_in[4];
    float* out = (float*)d_out;

    char* ws = (char*)d_ws;
    unsigned short* x_bf    = (unsigned short*)(ws);                 //  8 MB
    unsigned short* wqkv_t  = (unsigned short*)(ws + 8388608);       //  6 MB
    unsigned short* wproj_t = (unsigned short*)(ws + 14680064);      //  2 MB
    unsigned short* qkv     = (unsigned short*)(ws + 16777216);      // 24 MB
    unsigned short* ybuf    = (unsigned short*)(ws + 41943040);      //  8 MB

    cast_kernel<<<(M_ * C_) / 4 / 256, 256, 0, stream>>>(x, x_bf, M_ * C_);
    transpose_cast_kernel<<<dim3(3072 / 32, 1024 / 32), dim3(32, 8), 0, stream>>>(Wqkv, wqkv_t, 1024, 3072);
    transpose_cast_kernel<<<dim3(1024 / 32, 1024 / 32), dim3(32, 8), 0, stream>>>(Wproj, wproj_t, 1024, 1024);

    gemm_bt<0><<<dim3(M_ / 128, 3072 / 128), 256, 0, stream>>>(
        x_bf, wqkv_t, bqkv, qkv, nullptr, M_, 3072, 1024);

    attn_kernel<<<dim3(512), 256, 0, stream>>>(
        qkv, qkv + (size_t)BHTD_, qkv + 2 * (size_t)BHTD_, ybuf);

    gemm_bt<1><<<dim3(M_ / 128, 1024 / 128), 256, 0, stream>>>(
        ybuf, wproj_t, bproj, nullptr, out, M_, 1024, 1024);
}

// Round 8
// 126.537 us; speedup vs baseline: 1.2501x; 1.0563x over previous
//
#include <hip/hip_runtime.h>
#include <stdint.h>

#define B_ 2
#define T_ 2048
#define C_ 1024
#define H_ 16
#define D_ 64
#define M_ (B_*T_)
#define BHTD_ (B_*H_*T_*D_)

typedef __bf16 bf16x8 __attribute__((ext_vector_type(8)));
typedef __bf16 bf16x4 __attribute__((ext_vector_type(4)));
typedef float f32x4 __attribute__((ext_vector_type(4)));

static __device__ __forceinline__ unsigned short f32_bf16(float f) {
    unsigned int u = __float_as_uint(f);
    u += 0x7FFFu + ((u >> 16) & 1u);   // round-to-nearest-even
    return (unsigned short)(u >> 16);
}

// ---------------- cast f32 -> bf16 (vectorized) ----------------
__global__ void cast_kernel(const float* __restrict__ in, unsigned short* __restrict__ out, int n) {
    int i = (blockIdx.x * 256 + threadIdx.x) * 4;
    if (i >= n) return;
    float4 f = *(const float4*)(in + i);
    ushort4 o;
    o.x = f32_bf16(f.x); o.y = f32_bf16(f.y); o.z = f32_bf16(f.z); o.w = f32_bf16(f.w);
    *(ushort4*)(out + i) = o;
}

// ---------------- transpose+cast: W [K][N] f32 -> Wt [N][K] bf16 ----------------
__global__ void transpose_cast_kernel(const float* __restrict__ W, unsigned short* __restrict__ Wt,
                                      int K, int N) {
    __shared__ float tile[32][33];
    int n0 = blockIdx.x * 32, k0 = blockIdx.y * 32;
    int tx = threadIdx.x, ty = threadIdx.y;
    #pragma unroll
    for (int j = 0; j < 32; j += 8)
        tile[ty + j][tx] = W[(size_t)(k0 + ty + j) * N + n0 + tx];
    __syncthreads();
    #pragma unroll
    for (int j = 0; j < 32; j += 8)
        Wt[(size_t)(n0 + ty + j) * K + k0 + tx] = f32_bf16(tile[tx][ty + j]);
}

// ---------------- GEMM: C[M][N] = A[M][K](bf16) * Bt[N][K]^T(bf16) + bias ----------------
// 2-phase double-buffered global_load_lds staging: issue loads for tile k+1
// into buf^1 BEFORE computing tile k; ONE barrier per k-step (compiler drains
// vmcnt(0) at the barrier; the loads had the whole compute phase to land).
template<int EPI>
__global__ __launch_bounds__(256) void gemm_bt(
    const unsigned short* __restrict__ A,
    const unsigned short* __restrict__ Bt,
    const float* __restrict__ bias,
    unsigned short* __restrict__ out_bf16,
    float* __restrict__ out_f32,
    int M, int N, int K)
{
    __shared__ unsigned short As[2][128 * 32];
    __shared__ unsigned short Bs[2][128 * 32];
    int tid = threadIdx.x;
    int lane = tid & 63, wid = tid >> 6;
    int fr = lane & 15, fg = lane >> 4;
    int row0 = blockIdx.x * 128, col0 = blockIdx.y * 128;
    int wm = (wid >> 1) * 64, wn = (wid & 1) * 64;

    f32x4 acc[4][4];
    #pragma unroll
    for (int i = 0; i < 4; ++i)
        #pragma unroll
        for (int j = 0; j < 4; ++j)
            acc[i][j] = (f32x4){0.f, 0.f, 0.f, 0.f};

    const int srw = lane >> 2;
    const int scl = (lane & 3) * 8;
    const int c0 = wid * 2, c1 = wid * 2 + 1;

    auto stage = [&](int buf, int k0) {
        __builtin_amdgcn_global_load_lds(
            (const __attribute__((address_space(1))) void*)(A + (size_t)(row0 + c0 * 16 + srw) * K + k0 + scl),
            (__attribute__((address_space(3))) void*)(As[buf] + c0 * 512), 16, 0, 0);
        __builtin_amdgcn_global_load_lds(
            (const __attribute__((address_space(1))) void*)(A + (size_t)(row0 + c1 * 16 + srw) * K + k0 + scl),
            (__attribute__((address_space(3))) void*)(As[buf] + c1 * 512), 16, 0, 0);
        __builtin_amdgcn_global_load_lds(
            (const __attribute__((address_space(1))) void*)(Bt + (size_t)(col0 + c0 * 16 + srw) * K + k0 + scl),
            (__attribute__((address_space(3))) void*)(Bs[buf] + c0 * 512), 16, 0, 0);
        __builtin_amdgcn_global_load_lds(
            (const __attribute__((address_space(1))) void*)(Bt + (size_t)(col0 + c1 * 16 + srw) * K + k0 + scl),
            (__attribute__((address_space(3))) void*)(Bs[buf] + c1 * 512), 16, 0, 0);
    };

    stage(0, 0);
    __syncthreads();   // vmcnt(0) drained by compiler before barrier -> buf0 ready

    int cur = 0;
    for (int k0 = 0; k0 < K; k0 += 32) {
        if (k0 + 32 < K) stage(cur ^ 1, k0 + 32);   // issue next-tile loads EARLY

        bf16x8 af[4], bfr[4];
        #pragma unroll
        for (int i = 0; i < 4; ++i) {
            af[i]  = *(const bf16x8*)(As[cur] + (wm + i * 16 + fr) * 32 + fg * 8);
            bfr[i] = *(const bf16x8*)(Bs[cur] + (wn + i * 16 + fr) * 32 + fg * 8);
        }
        #pragma unroll
        for (int mi = 0; mi < 4; ++mi)
            #pragma unroll
            for (int ni = 0; ni < 4; ++ni)
                acc[mi][ni] = __builtin_amdgcn_mfma_f32_16x16x32_bf16(af[mi], bfr[ni], acc[mi][ni], 0, 0, 0);

        __syncthreads();   // drains next-tile loads (they landed under compute)
        cur ^= 1;
    }

    #pragma unroll
    for (int mi = 0; mi < 4; ++mi) {
        int rowb = row0 + wm + mi * 16 + fg * 4;
        #pragma unroll
        for (int ni = 0; ni < 4; ++ni) {
            int col = col0 + wn + ni * 16 + fr;
            float bv = bias[col];
            #pragma unroll
            for (int r = 0; r < 4; ++r) {
                float v = acc[mi][ni][r] + bv;
                int rr = rowb + r;
                if (EPI == 0) {
                    int part = col >> 10, c = col & 1023;
                    int h = c >> 6, d = c & 63;
                    int b = rr >> 11, t = rr & 2047;
                    if (part == 0) v *= 0.18033688011112042f;   // fold log2(e)/sqrt(D) into Q
                    size_t idx;
                    if (part == 2)
                        idx = (size_t)2 * BHTD_ + ((size_t)(b * H_ + h) * D_ + d) * T_ + t;
                    else
                        idx = (size_t)part * BHTD_ + ((size_t)(b * H_ + h) * T_ + t) * D_ + d;
                    out_bf16[idx] = f32_bf16(v);
                } else {
                    out_f32[(size_t)rr * N + col] = v;
                }
            }
        }
    }
}

// ---------------- causal flash attention v8: dual-stream, compiler-scheduled ----------------
// Same decomposition as v7 (balanced dual 64-row chunks, 33 stream-tiles/block,
// swapped-operand QK/PV, no-max softmax). Changes: no manual lgkmcnt/sched_barrier
// joins; code order hi-softmax -> hi-PV -> lo-softmax -> lo-PV with V^T frags
// hoisted, so PV-hi MFMA overlaps lo-stream softmax VALU.
__global__ __launch_bounds__(256) void attn_kernel(
    const unsigned short* __restrict__ qg,
    const unsigned short* __restrict__ kg,
    const unsigned short* __restrict__ vtg,  // [bh][D][T]
    unsigned short* __restrict__ y)
{
    const int id = blockIdx.x;
    const int xcd = id & 7, loc = id >> 3;
    const int bh = xcd * 4 + (loc & 3);      // 4 heads per XCD -> K/V L2-resident
    const int iq = loc >> 2;                 // [0,16)
    const int chlo = iq, chhi = 31 - iq;     // 64-row q chunks
    const int b = bh >> 4, h = bh & 15;
    const int tid = threadIdx.x, wid = tid >> 6, lane = tid & 63;
    const int fr = lane & 15, fg = lane >> 4;

    const unsigned short* qp = qg + (size_t)bh * (T_ * D_);
    const unsigned short* kp = kg + (size_t)bh * (T_ * D_);
    const unsigned short* vp = vtg + (size_t)bh * (D_ * T_);

    __shared__ __align__(16) char Ks[2][64 * 128];   // [kv][d] bf16, swizzled
    __shared__ __align__(16) char Vs[2][64 * 128];   // [d][kv] bf16, swizzled
    __shared__ __align__(16) char Ps[4][32 * 128];   // per-wave P: [stream*16+row][kv]
    char* Pw = Ps[wid];

    const int rhi = chhi * 64 + wid * 16;
    const int rlo = chlo * 64 + wid * 16;

    const int srow = tid >> 3;
    const int scb  = (tid & 7) * 16;
    const int sws  = scb ^ ((srow & 7) << 4);

    bf16x8 qhi[2], qlo[2];
    #pragma unroll
    for (int kd = 0; kd < 2; ++kd) {
        qhi[kd] = *(const bf16x8*)(qp + (size_t)(rhi + fr) * D_ + kd * 32 + fg * 8);
        qlo[kd] = *(const bf16x8*)(qp + (size_t)(rlo + fr) * D_ + kd * 32 + fg * 8);
    }

    f32x4 oHi[4], oLo[4];
    float lHi = 0.f, lLo = 0.f;
    #pragma unroll
    for (int n = 0; n < 4; ++n) {
        oHi[n] = (f32x4){0.f, 0.f, 0.f, 0.f};
        oLo[n] = (f32x4){0.f, 0.f, 0.f, 0.f};
    }

    const int ntk  = chhi + 1;
    const int ntlo = chlo + 1;

    // prologue: stage tile 0 into buffer 0
    {
        uint4 k0 = *(const uint4*)(kp + (size_t)srow        * D_ + (scb >> 1));
        uint4 k1 = *(const uint4*)(kp + (size_t)(srow + 32) * D_ + (scb >> 1));
        uint4 v0 = *(const uint4*)(vp + (size_t)srow        * T_ + (scb >> 1));
        uint4 v1 = *(const uint4*)(vp + (size_t)(srow + 32) * T_ + (scb >> 1));
        *(uint4*)(Ks[0] + srow * 128 + sws)        = k0;
        *(uint4*)(Ks[0] + (srow + 32) * 128 + sws) = k1;
        *(uint4*)(Vs[0] + srow * 128 + sws)        = v0;
        *(uint4*)(Vs[0] + (srow + 32) * 128 + sws) = v1;
    }
    __syncthreads();

    int cur = 0;
    for (int t = 0; t < ntk; ++t) {
        const int kv0 = t * 64;
        const int kv1 = (t + 1 < ntk) ? kv0 + 64 : kv0;

        // prefetch tile t+1 global->reg (lands under this tile's compute)
        uint4 pk0 = *(const uint4*)(kp + (size_t)(kv1 + srow)      * D_ + (scb >> 1));
        uint4 pk1 = *(const uint4*)(kp + (size_t)(kv1 + srow + 32) * D_ + (scb >> 1));
        uint4 pv0 = *(const uint4*)(vp + (size_t)srow        * T_ + kv1 + (scb >> 1));
        uint4 pv1 = *(const uint4*)(vp + (size_t)(srow + 32) * T_ + kv1 + (scb >> 1));

        const char* Kb = Ks[cur];
        const char* Vb = Vs[cur];
        const unsigned lsw = (unsigned)((fr & 7) << 4);
        const bool lo_act = (t < ntlo);      // block-uniform

        // ---- S^T = mfma(K, Q), both streams ----
        f32x4 sh[4], sl[4];
        #pragma unroll
        for (int n = 0; n < 4; ++n) {
            sh[n] = (f32x4){0.f, 0.f, 0.f, 0.f};
            sl[n] = (f32x4){0.f, 0.f, 0.f, 0.f};
        }
        #pragma unroll
        for (int kd = 0; kd < 2; ++kd)
            #pragma unroll
            for (int n = 0; n < 4; ++n) {
                bf16x8 kf = *(const bf16x8*)(Kb + (n * 16 + fr) * 128 +
                                             (((unsigned)(kd * 64 + fg * 16)) ^ lsw));
                sh[n] = __builtin_amdgcn_mfma_f32_16x16x32_bf16(kf, qhi[kd], sh[n], 0, 0, 0);
                if (lo_act)
                    sl[n] = __builtin_amdgcn_mfma_f32_16x16x32_bf16(kf, qlo[kd], sl[n], 0, 0, 0);
            }

        // ---- V^T frags hoisted (shared by both streams) ----
        bf16x8 vf[4][2];
        #pragma unroll
        for (int nd = 0; nd < 4; ++nd)
            #pragma unroll
            for (int kk = 0; kk < 2; ++kk)
                vf[nd][kk] = *(const bf16x8*)(Vb + (nd * 16 + fr) * 128 +
                                              (((unsigned)(kk * 64 + fg * 16)) ^ lsw));

        // ---- hi: softmax + P write ----
        {
            const bool masked = (t == chhi);
            const int qrow = rhi + fr;
            const unsigned prow = (unsigned)fr * 128;
            #pragma unroll
            for (int n = 0; n < 4; ++n) {
                float x0 = sh[n][0], x1 = sh[n][1], x2 = sh[n][2], x3 = sh[n][3];
                if (masked) {
                    const int kvb = kv0 + n * 16 + fg * 4;
                    if (kvb     > qrow) x0 = -1e30f;
                    if (kvb + 1 > qrow) x1 = -1e30f;
                    if (kvb + 2 > qrow) x2 = -1e30f;
                    if (kvb + 3 > qrow) x3 = -1e30f;
                }
                const float p0 = exp2f(x0), p1 = exp2f(x1);
                const float p2 = exp2f(x2), p3 = exp2f(x3);
                lHi += (p0 + p1) + (p2 + p3);
                bf16x4 pk4 = {(__bf16)p0, (__bf16)p1, (__bf16)p2, (__bf16)p3};
                *(uint2*)(Pw + ((prow + (unsigned)(n * 32 + fg * 8)) ^ lsw)) =
                    __builtin_bit_cast(uint2, pk4);
            }
        }
        // ---- hi: PV (reads only rows [0,16) -> compiler orders after hi writes) ----
        {
            const unsigned prow = (unsigned)fr * 128;
            #pragma unroll
            for (int kk = 0; kk < 2; ++kk) {
                bf16x8 pb = *(const bf16x8*)(Pw + ((prow + (unsigned)(kk * 64 + fg * 16)) ^ lsw));
                #pragma unroll
                for (int nd = 0; nd < 4; ++nd)
                    oHi[nd] = __builtin_amdgcn_mfma_f32_16x16x32_bf16(vf[nd][kk], pb, oHi[nd], 0, 0, 0);
            }
        }
        // ---- lo: softmax + P write ----
        if (lo_act) {
            const bool masked = (t == chlo);
            const int qrow = rlo + fr;
            const unsigned prow = (unsigned)(16 + fr) * 128;
            #pragma unroll
            for (int n = 0; n < 4; ++n) {
                float x0 = sl[n][0], x1 = sl[n][1], x2 = sl[n][2], x3 = sl[n][3];
                if (masked) {
                    const int kvb = kv0 + n * 16 + fg * 4;
                    if (kvb     > qrow) x0 = -1e30f;
                    if (kvb + 1 > qrow) x1 = -1e30f;
                    if (kvb + 2 > qrow) x2 = -1e30f;
                    if (kvb + 3 > qrow) x3 = -1e30f;
                }
                const float p0 = exp2f(x0), p1 = exp2f(x1);
                const float p2 = exp2f(x2), p3 = exp2f(x3);
                lLo += (p0 + p1) + (p2 + p3);
                bf16x4 pk4 = {(__bf16)p0, (__bf16)p1, (__bf16)p2, (__bf16)p3};
                *(uint2*)(Pw + ((prow + (unsigned)(n * 32 + fg * 8)) ^ lsw)) =
                    __builtin_bit_cast(uint2, pk4);
            }
            // ---- lo: PV ----
            const unsigned prow2 = (unsigned)(16 + fr) * 128;
            #pragma unroll
            for (int kk = 0; kk < 2; ++kk) {
                bf16x8 pb = *(const bf16x8*)(Pw + ((prow2 + (unsigned)(kk * 64 + fg * 16)) ^ lsw));
                #pragma unroll
                for (int nd = 0; nd < 4; ++nd)
                    oLo[nd] = __builtin_amdgcn_mfma_f32_16x16x32_bf16(vf[nd][kk], pb, oLo[nd], 0, 0, 0);
            }
        }

        // write prefetched tile into the other buffer, then barrier
        {
            char* Kn = Ks[cur ^ 1];
            char* Vn = Vs[cur ^ 1];
            *(uint4*)(Kn + srow * 128 + sws)        = pk0;
            *(uint4*)(Kn + (srow + 32) * 128 + sws) = pk1;
            *(uint4*)(Vn + srow * 128 + sws)        = pv0;
            *(uint4*)(Vn + (srow + 32) * 128 + sws) = pv1;
        }
        __syncthreads();
        cur ^= 1;
    }

    // ---- epilogue: reduce l over fg groups, normalize, packed stores ----
    #pragma unroll
    for (int s = 0; s < 2; ++s) {
        float rs = s ? lLo : lHi;
        rs += __shfl_xor(rs, 16);
        rs += __shfl_xor(rs, 32);
        const float inv = 1.f / rs;
        const int trow = (s ? rlo : rhi) + fr;
        f32x4* oT = s ? oLo : oHi;
        #pragma unroll
        for (int nd = 0; nd < 4; ++nd) {
            bf16x4 ov = {(__bf16)(oT[nd][0] * inv), (__bf16)(oT[nd][1] * inv),
                         (__bf16)(oT[nd][2] * inv), (__bf16)(oT[nd][3] * inv)};
            *(uint2*)(y + ((size_t)b * T_ + trow) * C_ + h * 64 + nd * 16 + fg * 4) =
                __builtin_bit_cast(uint2, ov);
        }
    }
}

// ---------------- launch ----------------
extern "C" void kernel_launch(void* const* d_in, const int* in_sizes, int n_in,
                              void* d_out, int out_size, void* d_ws, size_t ws_size,
                              hipStream_t stream) {
    const float* x     = (const float*)d_in[0];
    const float* Wqkv  = (const float*)d_in[1];
    const float* bqkv  = (const float*)d_in[2];
    const float* Wproj = (const float*)d_in[3];
    const float* bproj = (const float*)d_in[4];
    float* out = (float*)d_out;

    char* ws = (char*)d_ws;
    unsigned short* x_bf    = (unsigned short*)(ws);                 //  8 MB
    unsigned short* wqkv_t  = (unsigned short*)(ws + 8388608);       //  6 MB
    unsigned short* wproj_t = (unsigned short*)(ws + 14680064);      //  2 MB
    unsigned short* qkv     = (unsigned short*)(ws + 16777216);      // 24 MB
    unsigned short* ybuf    = (unsigned short*)(ws + 41943040);      //  8 MB

    cast_kernel<<<(M_ * C_) / 4 / 256, 256, 0, stream>>>(x, x_bf, M_ * C_);
    transpose_cast_kernel<<<dim3(3072 / 32, 1024 / 32), dim3(32, 8), 0, stream>>>(Wqkv, wqkv_t, 1024, 3072);
    transpose_cast_kernel<<<dim3(1024 / 32, 1024 / 32), dim3(32, 8), 0, stream>>>(Wproj, wproj_t, 1024, 1024);

    gemm_bt<0><<<dim3(M_ / 128, 3072 / 128), 256, 0, stream>>>(
        x_bf, wqkv_t, bqkv, qkv, nullptr, M_, 3072, 1024);

    attn_kernel<<<dim3(512), 256, 0, stream>>>(
        qkv, qkv + (size_t)BHTD_, qkv + 2 * (size_t)BHTD_, ybuf);

    gemm_bt<1><<<dim3(M_ / 128, 1024 / 128), 256, 0, stream>>>(
        ybuf, wproj_t, bproj, nullptr, out, M_, 1024, 1024);
}